// Round 1
// baseline (19189.738 us; speedup 1.0000x reference)
//
#include <hip/hip_runtime.h>

// Seq2seq LSTM + attention, fp32 baseline.
// Layout convention: all activations stored feature-major, batch-minor [dim][64]
// so that one wave (64 lanes) = 64 batch elements -> coalesced 256B loads,
// wave-uniform (scalar) weight loads.
//
// Workspace layout (floats), total ~29.6M floats = ~118.4 MB:
//   xT      [512][256][64]   transposed input
//   encH    [513][512][64]   h0 + all encoder hidden states (slot t+1 = h after step t)
//   cT      [512][64]        cell state (encoder then decoder, continuous)
//   We_pT   [512][64], Wh_pT [512][64], WahT [64][64], WaeT [64][64]
//   encProj [64][512][64]    enc_proj[b][s][h]
//   attnPre [64][512][64]    enc_proj @ Wa_e.T + ba  (ba pre-folded)
//   hbuf0/1 [512][64]        decoder h double buffer
//   ctxT    [64][64]         context, [h][b]
//   outT    [256][64]        decoder output (feedback x), [f][b]

namespace {

__device__ __forceinline__ float fsigmoid(float x) {
    return 1.0f / (1.0f + __expf(-x));
}
__device__ __forceinline__ float ftanh(float x) {
    // safe at +/-inf: exp(2x)=inf -> 1 ; exp(2x)=0 -> -1
    float e = __expf(2.0f * x);
    return 1.0f - 2.0f / (e + 1.0f);
}

// ---- transpose input_seq (B,S,F) -> xT[s][f][b] -------------------------
__global__ __launch_bounds__(256) void k_transpose_input(
    const float* __restrict__ in, float* __restrict__ xT)
{
    __shared__ float tile[64][65];
    int s  = blockIdx.x >> 2;          // 0..511
    int f0 = (blockIdx.x & 3) * 64;    // 0,64,128,192
    int lane = threadIdx.x & 63;
    int r0   = threadIdx.x >> 6;
    for (int r = r0; r < 64; r += 4)   // r = batch row
        tile[r][lane] = in[(size_t)r * (512 * 256) + s * 256 + f0 + lane];
    __syncthreads();
    for (int r = r0; r < 64; r += 4)   // r = feature row, lane = batch
        xT[((size_t)s * 256 + f0 + r) * 64 + lane] = tile[lane][r];
}

// ---- small weight/state transposes --------------------------------------
__global__ __launch_bounds__(256) void k_prep(
    const float* __restrict__ We_p, const float* __restrict__ Wh_p,
    const float* __restrict__ h0,   const float* __restrict__ c0,
    const float* __restrict__ Wa,
    float* __restrict__ We_pT, float* __restrict__ Wh_pT,
    float* __restrict__ encH0, float* __restrict__ cT,
    float* __restrict__ WahT,  float* __restrict__ WaeT)
{
    int idx = blockIdx.x * blockDim.x + threadIdx.x;
    const int total = 32768 * 4 + 4096 * 2;
    for (; idx < total; idx += gridDim.x * blockDim.x) {
        if (idx < 32768) {                       // We_pT[u][h] = We_p[h][u]
            int u = idx >> 6, h = idx & 63;
            We_pT[idx] = We_p[h * 512 + u];
        } else if (idx < 65536) {                // Wh_pT[k][i] = Wh_p[i][k]
            int i2 = idx - 32768; int k = i2 >> 6, i = i2 & 63;
            Wh_pT[i2] = Wh_p[i * 512 + k];
        } else if (idx < 98304) {                // encH slot0 [u][b] = h0[b][u]
            int i2 = idx - 65536; int u = i2 >> 6, b = i2 & 63;
            encH0[i2] = h0[b * 512 + u];
        } else if (idx < 131072) {               // cT[u][b] = c0[b][u]
            int i2 = idx - 98304; int u = i2 >> 6, b = i2 & 63;
            cT[i2] = c0[b * 512 + u];
        } else if (idx < 135168) {               // WahT[j][i] = Wa[i][j]
            int i2 = idx - 131072; int j = i2 >> 6, i = i2 & 63;
            WahT[i2] = Wa[i * 128 + j];
        } else {                                 // WaeT[h2][h] = Wa[h][64+h2]
            int i2 = idx - 135168; int h2 = i2 >> 6, h = i2 & 63;
            WaeT[i2] = Wa[h * 128 + 64 + h2];
        }
    }
}

// ---- one LSTM step, block = 512 thr (8 waves), 2 hidden units / block ----
// K=768 (256 x-part + 512 h-part) split 8 ways across waves, LDS reduce.
__device__ __forceinline__ void lstm_block(
    int ublock, int tid,
    const float* __restrict__ x,     // [256][64]
    const float* __restrict__ hprev, // [512][64]
    float* __restrict__ hout,        // [512][64]
    float* __restrict__ c,           // [512][64]
    const float* __restrict__ Wih,   // [2048][256]
    const float* __restrict__ Whh,   // [2048][512]
    const float* __restrict__ bias,  // [2048]
    float* smem)                     // 4608 floats
{
    int lane = tid & 63;
    int w    = tid >> 6;             // 0..7
    int u0   = ublock * 2;
    float acc[2][4] = {{0.f,0.f,0.f,0.f},{0.f,0.f,0.f,0.f}};
    int ks = w * 96, ke = ks + 96;
    int xe = ke < 256 ? ke : 256;
    #pragma unroll 4
    for (int k = ks; k < xe; ++k) {
        float xv = x[k * 64 + lane];
        #pragma unroll
        for (int uu = 0; uu < 2; ++uu)
            #pragma unroll
            for (int g = 0; g < 4; ++g)
                acc[uu][g] = fmaf(xv, Wih[(size_t)(g * 512 + u0 + uu) * 256 + k], acc[uu][g]);
    }
    int hs = ks > 256 ? ks : 256;
    #pragma unroll 4
    for (int k = hs; k < ke; ++k) {
        float hv = hprev[(k - 256) * 64 + lane];
        #pragma unroll
        for (int uu = 0; uu < 2; ++uu)
            #pragma unroll
            for (int g = 0; g < 4; ++g)
                acc[uu][g] = fmaf(hv, Whh[(size_t)(g * 512 + u0 + uu) * 512 + (k - 256)], acc[uu][g]);
    }
    float* part = smem;          // [8][2][4][64]
    float* gsum = smem + 4096;   // [2][4][64]
    #pragma unroll
    for (int uu = 0; uu < 2; ++uu)
        #pragma unroll
        for (int g = 0; g < 4; ++g)
            part[((w * 2 + uu) * 4 + g) * 64 + lane] = acc[uu][g];
    __syncthreads();
    {
        int b = tid & 63, g = (tid >> 6) & 3, uu = tid >> 8;
        float s = 0.f;
        #pragma unroll
        for (int ww = 0; ww < 8; ++ww)
            s += part[((ww * 2 + uu) * 4 + g) * 64 + b];
        gsum[(uu * 4 + g) * 64 + b] = s;
    }
    __syncthreads();
    if (tid < 128) {
        int b = tid & 63, uu = tid >> 6;
        int u = u0 + uu;
        float gi = gsum[(uu * 4 + 0) * 64 + b] + bias[u];
        float gf = gsum[(uu * 4 + 1) * 64 + b] + bias[512 + u];
        float gg = gsum[(uu * 4 + 2) * 64 + b] + bias[1024 + u];
        float go = gsum[(uu * 4 + 3) * 64 + b] + bias[1536 + u];
        float si = fsigmoid(gi), sf = fsigmoid(gf), so = fsigmoid(go);
        float tg = ftanh(gg);
        float cn = sf * c[u * 64 + b] + si * tg;
        c[u * 64 + b] = cn;
        hout[u * 64 + b] = so * ftanh(cn);
    }
}

__global__ __launch_bounds__(512) void k_lstm_step(
    const float* __restrict__ x, const float* __restrict__ hprev,
    float* __restrict__ hout, float* __restrict__ c,
    const float* __restrict__ Wih, const float* __restrict__ Whh,
    const float* __restrict__ bias)
{
    __shared__ float smem[4608];
    lstm_block(blockIdx.x, threadIdx.x, x, hprev, hout, c, Wih, Whh, bias, smem);
}

// ---- enc_proj + enc_attn (ba folded in), one parallel pass ---------------
// wave handles (b, 8 consecutive s); lane = h. encH reads are wave-uniform.
__global__ __launch_bounds__(256) void k_proj_attn(
    const float* __restrict__ encH,  const float* __restrict__ We_pT,
    const float* __restrict__ be_p,  const float* __restrict__ WaeT,
    const float* __restrict__ ba,
    float* __restrict__ encProj, float* __restrict__ attnPre)
{
    int lane = threadIdx.x & 63;
    int w    = threadIdx.x >> 6;
    int wid  = blockIdx.x * 4 + w;   // 0..4095
    int b    = wid >> 6;
    int soct = wid & 63;             // covers s = soct*8 .. soct*8+7
    float acc[8];
    float bep = be_p[lane];
    #pragma unroll
    for (int j = 0; j < 8; ++j) acc[j] = bep;
    const float* hbase = encH + (size_t)(soct * 8 + 1) * 32768 + b;
    for (int u = 0; u < 512; ++u) {
        float wv = We_pT[u * 64 + lane];
        #pragma unroll
        for (int j = 0; j < 8; ++j)
            acc[j] = fmaf(hbase[(size_t)j * 32768 + u * 64], wv, acc[j]);
    }
    #pragma unroll
    for (int j = 0; j < 8; ++j)
        encProj[((size_t)b * 512 + soct * 8 + j) * 64 + lane] = acc[j];
    #pragma unroll
    for (int j = 0; j < 8; ++j) {
        float aa = ba[lane];
        for (int h2 = 0; h2 < 64; ++h2)
            aa = fmaf(__shfl(acc[j], h2), WaeT[h2 * 64 + lane], aa);
        attnPre[((size_t)b * 512 + soct * 8 + j) * 64 + lane] = aa;
    }
}

// ---- decoder: fused attention (64 blocks) + LSTM (256 blocks) ------------
__global__ __launch_bounds__(512) void k_dec_fused(
    const float* __restrict__ x, const float* __restrict__ hcur,
    float* __restrict__ hnext, float* __restrict__ c,
    const float* __restrict__ Wih, const float* __restrict__ Whh,
    const float* __restrict__ bias,
    const float* __restrict__ Wh_pT, const float* __restrict__ bh_p,
    const float* __restrict__ WahT,  const float* __restrict__ v,
    const float* __restrict__ attnPre, const float* __restrict__ encProj,
    float* __restrict__ ctxT)
{
    __shared__ float smem[4608];
    int tid = threadIdx.x;
    if (blockIdx.x < 256) {
        lstm_block(blockIdx.x, tid, x, hcur, hnext, c, Wih, Whh, bias, smem);
        return;
    }
    // ---- attention for batch b (uses OLD h = hcur) ----
    int b = blockIdx.x - 256;
    int lane = tid & 63, w = tid >> 6;
    float* hq     = smem;          // 64
    float* hWa    = smem + 64;     // 64
    float* scores = smem + 128;    // 512
    float* part   = smem + 640;    // 8*64
    float* red    = smem + 1152;   // 16
    // phase 1: hq = h @ Wh_p.T + bh_p
    {
        float p = 0.f;
        int k0 = w * 64;
        #pragma unroll 4
        for (int kk = 0; kk < 64; ++kk) {
            int k = k0 + kk;
            p = fmaf(hcur[k * 64 + b], Wh_pT[k * 64 + lane], p);
        }
        part[w * 64 + lane] = p;
    }
    __syncthreads();
    if (tid < 64) {
        float s = bh_p[tid];
        #pragma unroll
        for (int ww = 0; ww < 8; ++ww) s += part[ww * 64 + tid];
        hq[tid] = s;
    }
    __syncthreads();
    // phase 2: hWa = hq @ Wa_h.T
    if (tid < 64) {
        float s = 0.f;
        for (int j = 0; j < 64; ++j)
            s = fmaf(hq[j], WahT[j * 64 + tid], s);
        hWa[tid] = s;
    }
    __syncthreads();
    // phase 3: scores[s] = v . tanh(hWa + attnPre[b][s][:])
    {
        float hw = hWa[lane];
        float vv = v[lane];
        for (int s2 = w; s2 < 512; s2 += 8) {
            float e = ftanh(hw + attnPre[((size_t)b * 512 + s2) * 64 + lane]) * vv;
            #pragma unroll
            for (int off = 32; off > 0; off >>= 1)
                e += __shfl_down(e, off);
            if (lane == 0) scores[s2] = e;
        }
    }
    __syncthreads();
    // phase 4: softmax over 512 scores
    float sc = scores[tid];
    float m = sc;
    #pragma unroll
    for (int off = 32; off > 0; off >>= 1)
        m = fmaxf(m, __shfl_xor(m, off));
    if (lane == 0) red[w] = m;
    __syncthreads();
    if (tid == 0) {
        float mm = red[0];
        for (int ww = 1; ww < 8; ++ww) mm = fmaxf(mm, red[ww]);
        red[8] = mm;
    }
    __syncthreads();
    float M = red[8];
    float ex = __expf(sc - M);
    scores[tid] = ex;
    float ssum = ex;
    #pragma unroll
    for (int off = 32; off > 0; off >>= 1)
        ssum += __shfl_xor(ssum, off);
    if (lane == 0) red[w] = ssum;
    __syncthreads();
    if (tid == 0) {
        float tt = 0.f;
        for (int ww = 0; ww < 8; ++ww) tt += red[ww];
        red[8] = 1.0f / tt;
    }
    __syncthreads();
    float inv = red[8];
    // phase 5: ctx[h] = sum_s aw[s] * encProj[b][s][h]
    {
        float a = 0.f;
        for (int s2 = w; s2 < 512; s2 += 8)
            a = fmaf(scores[s2], encProj[((size_t)b * 512 + s2) * 64 + lane], a);
        part[w * 64 + lane] = a;
    }
    __syncthreads();
    if (tid < 64) {
        float s = 0.f;
        #pragma unroll
        for (int ww = 0; ww < 8; ++ww) s += part[ww * 64 + tid];
        ctxT[tid * 64 + b] = s * inv;
    }
}

// ---- out = [h_new, ctx] @ Wo.T + bo ; writes feedback x and d_out col ----
__global__ __launch_bounds__(256) void k_dec_out(
    const float* __restrict__ h, const float* __restrict__ ctxT,
    const float* __restrict__ Wo, const float* __restrict__ bo,
    float* __restrict__ outT, float* __restrict__ dout, int t)
{
    int lane = threadIdx.x & 63;
    int w    = threadIdx.x >> 6;
    int f    = blockIdx.x * 4 + w;   // 0..255
    float acc = bo[f];
    const float* wrow = Wo + (size_t)f * 576;
    #pragma unroll 4
    for (int k = 0; k < 512; ++k)
        acc = fmaf(h[k * 64 + lane], wrow[k], acc);
    #pragma unroll 4
    for (int k = 0; k < 64; ++k)
        acc = fmaf(ctxT[k * 64 + lane], wrow[512 + k], acc);
    outT[f * 64 + lane] = acc;
    if (f == 255) dout[lane * 96 + t] = acc;   // d_out[b][t], b = lane
}

} // namespace

extern "C" void kernel_launch(void* const* d_in, const int* in_sizes, int n_in,
                              void* d_out, int out_size, void* d_ws, size_t ws_size,
                              hipStream_t stream)
{
    (void)in_sizes; (void)n_in; (void)out_size; (void)ws_size;
    const float* input_seq = (const float*)d_in[0];
    const float* h0     = (const float*)d_in[1];
    const float* c0     = (const float*)d_in[2];
    const float* W_ih_e = (const float*)d_in[3];
    const float* W_hh_e = (const float*)d_in[4];
    const float* b_e    = (const float*)d_in[5];
    const float* W_ih_d = (const float*)d_in[6];
    const float* W_hh_d = (const float*)d_in[7];
    const float* b_d    = (const float*)d_in[8];
    const float* We_p   = (const float*)d_in[9];
    const float* be_p   = (const float*)d_in[10];
    const float* Wh_p   = (const float*)d_in[11];
    const float* bh_p   = (const float*)d_in[12];
    const float* Wa     = (const float*)d_in[13];
    const float* ba     = (const float*)d_in[14];
    const float* v      = (const float*)d_in[15];
    const float* Wo     = (const float*)d_in[16];
    const float* bo     = (const float*)d_in[17];
    float* out = (float*)d_out;

    float* ws      = (float*)d_ws;
    float* xT      = ws;                      // 8388608
    float* encH    = xT + 8388608;            // 513*32768 = 16809984
    float* cT      = encH + 16809984;         // 32768
    float* We_pT   = cT + 32768;              // 32768
    float* Wh_pT   = We_pT + 32768;           // 32768
    float* WahT    = Wh_pT + 32768;           // 4096
    float* WaeT    = WahT + 4096;             // 4096
    float* encProj = WaeT + 4096;             // 2097152
    float* attnPre = encProj + 2097152;       // 2097152
    float* hbuf0   = attnPre + 2097152;       // 32768
    float* hbuf1   = hbuf0 + 32768;           // 32768
    float* ctxT    = hbuf1 + 32768;           // 4096
    float* outT    = ctxT + 4096;             // 16384  -> total 29585408 floats

    k_transpose_input<<<2048, 256, 0, stream>>>(input_seq, xT);
    k_prep<<<544, 256, 0, stream>>>(We_p, Wh_p, h0, c0, Wa,
                                    We_pT, Wh_pT, encH, cT, WahT, WaeT);
    // encoder: 512 sequential steps; encH slot t -> slot t+1
    for (int t = 0; t < 512; ++t)
        k_lstm_step<<<256, 512, 0, stream>>>(xT + (size_t)t * 16384,
                                             encH + (size_t)t * 32768,
                                             encH + (size_t)(t + 1) * 32768,
                                             cT, W_ih_e, W_hh_e, b_e);
    k_proj_attn<<<1024, 256, 0, stream>>>(encH, We_pT, be_p, WaeT, ba,
                                          encProj, attnPre);
    // decoder: 96 sequential steps
    for (int t = 0; t < 96; ++t) {
        const float* x  = (t == 0) ? (xT + (size_t)511 * 16384) : outT;
        const float* hc = (t == 0) ? (encH + (size_t)512 * 32768)
                                   : ((t & 1) ? hbuf0 : hbuf1);
        float* hn = (t & 1) ? hbuf1 : hbuf0;
        k_dec_fused<<<320, 512, 0, stream>>>(x, hc, hn, cT, W_ih_d, W_hh_d, b_d,
                                             Wh_pT, bh_p, WahT, v,
                                             attnPre, encProj, ctxT);
        k_dec_out<<<64, 256, 0, stream>>>(hn, ctxT, Wo, bo, outT, out, t);
    }
}